// Round 5
// baseline (221.808 us; speedup 1.0000x reference)
//
#include <hip/hip_runtime.h>
#include <hip/hip_bf16.h>
#include <cstdint>
#include <cstddef>
#include <type_traits>

// B=4, S=2048, D=1024 causal attention head, fp32 in/out.
// R11: shared 256^2 core gets A-operand triple-buffering (distance-2 K-tiles).
// R10 counters: pv256 bank-conflicts 0, FETCH down, but 1120cyc/phase stall —
// A1/A3 had 1-phase issue-to-use cover; P streams from L3/HBM (~600-900cyc).
// New schedule: A(t+2) issued during tile t (5-8 phase cover), B(t+1) in
// ph0/ph1 (2.5-3.5 phase cover), single end-of-tile vmcnt(2). LDS 160KB.

using bf16 = __hip_bfloat16;
typedef __attribute__((ext_vector_type(8))) short short8;   // 8 bf16 (A/B frag)
typedef __attribute__((ext_vector_type(4))) float f32x4;    // C/D frag

#define NB 4
#define SS 2048
#define DD 1024

// ---------------------------------------------------------------- async 16B global->LDS
__device__ __forceinline__ void async_lds16(const bf16* g, bf16* l) {
  __builtin_amdgcn_global_load_lds(
      (const __attribute__((address_space(1))) void*)g,
      (__attribute__((address_space(3))) void*)l,
      16, 0, 0);  // HW writes lane i's 16B to ldsbase + i*16
}

struct alignas(8) bf16x4s { bf16 a, b, c, d; };

// ---------------------------------------------------------------- fused prep
__global__ __launch_bounds__(256) void prep_kernel(const float* __restrict__ x,
                                                   bf16* __restrict__ xb,
                                                   const float* __restrict__ qk,
                                                   bf16* __restrict__ qkT,
                                                   const float* __restrict__ ov,
                                                   bf16* __restrict__ ovT,
                                                   float* __restrict__ l) {
  __shared__ bf16 tile[64][65];
  const int bx = blockIdx.x;
  if (bx < 8192) {
    int i = (bx * 256 + threadIdx.x) * 4;
    float4 v = *(const float4*)(x + i);
    bf16x4s o{__float2bfloat16(v.x), __float2bfloat16(v.y),
              __float2bfloat16(v.z), __float2bfloat16(v.w)};
    *(bf16x4s*)(xb + i) = o;
  } else if (bx < 8704) {
    const int idx = bx - 8192;
    const float* in = (idx & 256) ? ov : qk;
    bf16* out = (idx & 256) ? ovT : qkT;
    const int rem = idx & 255;
    const int tbx = (rem & 15) * 64;
    const int tby = (rem >> 4) * 64;
    const int tc = threadIdx.x & 63;
    const int tr = threadIdx.x >> 6;
#pragma unroll
    for (int r = tr; r < 64; r += 4)
      tile[tc][r] = __float2bfloat16(in[(size_t)(tby + r) * DD + tbx + tc]);
    __syncthreads();
#pragma unroll
    for (int r = tr; r < 64; r += 4)
      out[(size_t)(tbx + r) * DD + tby + tc] = tile[r][tc];
  } else {
    const int t = (bx - 8704) * 256 + threadIdx.x;
    f32x4 z = {0.f, 0.f, 0.f, 0.f};
    *(f32x4*)(l + t * 4) = z;
  }
}

// ================================================================ 256^2 phased core
// C = A[M,K] * Bt[N,K]^T at (m0,n0). 256x256 tile, BK=64, 8 waves (2Mx4N),
// per-wave output 128x64 (acc[8][4]). 4 phases/K-tile, T2 chunk-XOR swizzle,
// setprio (T5). A: 3 LDS buffers (kt%3), loads for tile t+2 issued during t.
// B: 2 buffers (kt&1), loads for t+1 in ph0/ph1. Single end-of-tile vmcnt(2):
// retires through B2B3(t+1) (issued ph1, ~3-phase cover), leaves A1A3(t+2).
// A-side cover 5-8 phases -> hides L3/HBM streaming latency (pv's P, sc's Qb).
// EPI: 1 = bf16 store; 2 = exp(acc/32) causal -> bf16 + rowsum atomics;
//      3 = acc * (1/l[row]) -> f32.
template <int EPI>
__device__ __forceinline__ void gemm256_core(const bf16* __restrict__ Ab,
                                             const bf16* __restrict__ Bb,
                                             void* __restrict__ C,
                                             int N, int K, int m0, int n0, int nk,
                                             bf16* As, bf16* Bs,
                                             float* __restrict__ l) {
  const int lane = threadIdx.x & 63;
  const int wave = threadIdx.x >> 6;   // 0..7
  const int wr   = wave >> 2;          // 0..1 -> rows wr*128
  const int wc   = wave & 3;           // 0..3 -> cols wc*64
  const int quad = lane >> 4;
  const int r    = lane & 15;

  f32x4 acc[8][4];
#pragma unroll
  for (int i = 0; i < 8; ++i)
#pragma unroll
    for (int n = 0; n < 4; ++n) acc[i][n] = f32x4{0.f, 0.f, 0.f, 0.f};

  const int lrow = lane >> 3;
  const int lsw  = (lane & 7) ^ lrow;          // pre-swizzled source chunk
  const long long a_lane = (long long)(m0 + wave * 8 + lrow) * K + lsw * 8;
  const long long b_lane = (long long)(n0 + wave * 8 + lrow) * K + lsw * 8;

  auto stageA = [&](int kt, int rnd, int buf) {
    async_lds16(Ab + a_lane + (long long)(rnd * 64) * K + (long long)kt * 64,
                As + buf * 16384 + (rnd * 64 + wave * 8) * 64);
  };
  auto stageB = [&](int kt, int rnd, int buf) {
    async_lds16(Bb + b_lane + (long long)(rnd * 64) * K + (long long)kt * 64,
                Bs + buf * 16384 + (rnd * 64 + wave * 8) * 64);
  };

  // prologue: A(0)->bufA0, B(0)->bufB0, A(1)->bufA1. vmcnt(4) keeps A(1) in flight.
  stageA(0, 0, 0); stageA(0, 2, 0); stageA(0, 1, 0); stageA(0, 3, 0);
  stageB(0, 0, 0); stageB(0, 1, 0); stageB(0, 2, 0); stageB(0, 3, 0);
  if (nk > 1) {
    stageA(1, 0, 1); stageA(1, 2, 1); stageA(1, 1, 1); stageA(1, 3, 1);
    asm volatile("s_waitcnt vmcnt(4)" ::: "memory");
  } else {
    asm volatile("s_waitcnt vmcnt(0)" ::: "memory");
  }
  asm volatile("s_barrier" ::: "memory");

  const int ca0 = (quad ^ (r & 7)) * 8;        // kh=0 swizzled chunk offset
  const int ca1 = ((4 + quad) ^ (r & 7)) * 8;  // kh=1

  int ba = 0;                                  // A buffer for tile kt (kt % 3)
  for (int kt = 0; kt < nk; ++kt) {
    const int bb  = kt & 1;                    // B buffer for tile kt
    const int bb1 = bb ^ 1;                    // B buffer for tile kt+1
    int ba2 = ba + 2; if (ba2 >= 3) ba2 -= 3;  // A buffer for tile kt+2
    const bool hnA = (kt + 2 < nk);
    const bool hnB = (kt + 1 < nk);
    const bf16* Abuf = As + ba * 16384 + (wr * 128) * 64;
    const bf16* Bbuf = Bs + bb * 16384 + (wc * 64) * 64;

    auto phase = [&](auto RHC, int ca, auto&& stg, bool tail) {
      constexpr int RH = decltype(RHC)::value;
      short8 af[4], bfr[4];
#pragma unroll
      for (int m = 0; m < 4; ++m)
        af[m] = *(const short8*)(Abuf + (RH * 64 + m * 16 + r) * 64 + ca);
#pragma unroll
      for (int n = 0; n < 4; ++n)
        bfr[n] = *(const short8*)(Bbuf + (n * 16 + r) * 64 + ca);
      stg();
      asm volatile("s_barrier" ::: "memory");
      asm volatile("s_waitcnt lgkmcnt(0)" ::: "memory");
      __builtin_amdgcn_sched_barrier(0);
      __builtin_amdgcn_s_setprio(1);
#pragma unroll
      for (int m = 0; m < 4; ++m)
#pragma unroll
        for (int n = 0; n < 4; ++n)
          acc[RH * 4 + m][n] = __builtin_amdgcn_mfma_f32_16x16x32_bf16(
              af[m], bfr[n], acc[RH * 4 + m][n], 0, 0, 0);
      __builtin_amdgcn_s_setprio(0);
      if (tail) {
        if (hnA)      asm volatile("s_waitcnt vmcnt(2)" ::: "memory");
        else if (hnB) asm volatile("s_waitcnt vmcnt(0)" ::: "memory");
      }
      asm volatile("s_barrier" ::: "memory");
    };

    phase(std::integral_constant<int, 0>{}, ca0,
          [&] {
            if (hnA) { stageA(kt + 2, 0, ba2); stageA(kt + 2, 2, ba2); }
            if (hnB) { stageB(kt + 1, 0, bb1); stageB(kt + 1, 1, bb1); }
          }, false);
    phase(std::integral_constant<int, 1>{}, ca0,
          [&] { if (hnB) { stageB(kt + 1, 2, bb1); stageB(kt + 1, 3, bb1); } }, false);
    phase(std::integral_constant<int, 0>{}, ca1, [&] {}, false);
    phase(std::integral_constant<int, 1>{}, ca1,
          [&] { if (hnA) { stageA(kt + 2, 1, ba2); stageA(kt + 2, 3, ba2); } }, true);

    if (++ba == 3) ba = 0;
  }

  // epilogue: C/D layout col = lane&15, row = quad*4 + reg (verified m89/m91)
#pragma unroll
  for (int i = 0; i < 8; ++i) {
    const int row0 = m0 + wr * 128 + i * 16 + quad * 4;
    if (EPI == 1) {
#pragma unroll
      for (int n = 0; n < 4; ++n) {
        const int col = n0 + wc * 64 + n * 16 + r;
#pragma unroll
        for (int q = 0; q < 4; ++q)
          ((bf16*)C)[(long long)(row0 + q) * N + col] = __float2bfloat16(acc[i][n][q]);
      }
    } else if (EPI == 2) {
      float qs[4] = {0.f, 0.f, 0.f, 0.f};
#pragma unroll
      for (int n = 0; n < 4; ++n) {
        const int col = n0 + wc * 64 + n * 16 + r;
#pragma unroll
        for (int q = 0; q < 4; ++q) {
          const int row = row0 + q;
          float v = (col <= row) ? __expf(acc[i][n][q] * 0.03125f) : 0.0f;
          ((bf16*)C)[(long long)row * N + col] = __float2bfloat16(v);
          qs[q] += v;
        }
      }
#pragma unroll
      for (int q = 0; q < 4; ++q) {
#pragma unroll
        for (int off = 1; off < 16; off <<= 1) qs[q] += __shfl_xor(qs[q], off, 64);
        if (r == 0) atomicAdd(&l[row0 + q], qs[q]);
      }
    } else {  // EPI == 3
      float rs[4];
#pragma unroll
      for (int q = 0; q < 4; ++q) rs[q] = 1.0f / l[row0 + q];
#pragma unroll
      for (int n = 0; n < 4; ++n) {
        const int col = n0 + wc * 64 + n * 16 + r;
#pragma unroll
        for (int q = 0; q < 4; ++q)
          ((float*)C)[(long long)(row0 + q) * N + col] = acc[i][n][q] * rs[q];
      }
    }
  }
}

// ---------------------------------------------------------------- merged Q + V GEMM (256^2)
__global__ __launch_bounds__(512, 2) void gemm_qv256(const bf16* __restrict__ xb,
                                                     const bf16* __restrict__ qkT,
                                                     const bf16* __restrict__ ovT,
                                                     bf16* __restrict__ Qb,
                                                     bf16* __restrict__ Vt) {
  extern __shared__ bf16 lds[];
  bf16* As = lds;            // [3][256][64] = 96KB
  bf16* Bs = lds + 49152;    // [2][256][64] = 64KB
  const long long SD = (long long)SS * DD;
  const int z = blockIdx.z;
  if (z < 4) {
    const int bn = blockIdx.x & 3, bm = blockIdx.x >> 2;
    gemm256_core<1>(xb + z * SD, qkT, Qb + z * SD, DD, DD, bm * 256, bn * 256, 16,
                    As, Bs, nullptr);
  } else {
    const int bm = blockIdx.x & 3, bn = blockIdx.x >> 2;
    gemm256_core<1>(ovT, xb + (z - 4) * SD, Vt + (z - 4) * SD, SS, DD, bm * 256, bn * 256, 16,
                    As, Bs, nullptr);
  }
}

// ---------------------------------------------------------------- scores GEMM (256^2) + exp/mask/rowsum
__global__ __launch_bounds__(512, 2) void gemm_sc256(const bf16* __restrict__ Qb,
                                                     const bf16* __restrict__ xb,
                                                     bf16* __restrict__ P,
                                                     float* __restrict__ l) {
  extern __shared__ bf16 lds[];
  bf16* As = lds;
  bf16* Bs = lds + 49152;
  const long long SD = (long long)SS * DD;
  const long long SSQ = (long long)SS * SS;
  const int t = blockIdx.x;
  int bm = (int)((sqrtf(8.0f * (float)t + 1.0f) - 1.0f) * 0.5f);
  while ((bm + 1) * (bm + 2) / 2 <= t) ++bm;
  while (bm * (bm + 1) / 2 > t) --bm;
  const int bn = t - bm * (bm + 1) / 2;
  const int b = blockIdx.z;
  gemm256_core<2>(Qb + b * SD, xb + b * SD, P + b * SSQ, SS, DD, bm * 256, bn * 256, 16,
                  As, Bs, l + b * SS);
}

// ---------------------------------------------------------------- PV GEMM (256^2) + fused 1/l
__global__ __launch_bounds__(512, 2) void gemm_pv256(const bf16* __restrict__ P,
                                                     const bf16* __restrict__ Vt,
                                                     const float* __restrict__ l,
                                                     float* __restrict__ out) {
  extern __shared__ bf16 lds[];
  bf16* As = lds;
  bf16* Bs = lds + 49152;
  const long long SD = (long long)SS * DD;
  const long long SSQ = (long long)SS * SS;
  const int bx = blockIdx.x & 3;
  const int bm = blockIdx.x >> 2;
  const int b = blockIdx.z;
  gemm256_core<3>(P + b * SSQ, Vt + b * SD, out + b * SD, DD, SS,
                  bm * 256, bx * 256, 4 * (bm + 1), As, Bs, (float*)l + b * SS);
}

// ---------------------------------------------------------------- launch
extern "C" void kernel_launch(void* const* d_in, const int* in_sizes, int n_in,
                              void* d_out, int out_size, void* d_ws, size_t ws_size,
                              hipStream_t stream) {
  const float* x  = (const float*)d_in[0];  // [4,2048,1024]
  const float* qk = (const float*)d_in[1];  // [1024,1024]
  const float* ov = (const float*)d_in[2];  // [1024,1024]
  float* out = (float*)d_out;               // [4,2048,1024] fp32

  char* ws = (char*)d_ws;
  const size_t MB = 1ull << 20;
  bf16*  xb  = (bf16*)(ws + 0);          // 16 MB
  bf16*  qkT = (bf16*)(ws + 16 * MB);    //  2 MB
  bf16*  ovT = (bf16*)(ws + 18 * MB);    //  2 MB
  bf16*  Qb  = (bf16*)(ws + 20 * MB);    // 16 MB
  bf16*  Vt  = (bf16*)(ws + 36 * MB);    // 16 MB  V^T per batch [D, S]
  bf16*  P   = (bf16*)(ws + 52 * MB);    // 32 MB  P' = exp(s/32) bf16
  float* l   = (float*)(ws + 84 * MB);   // 32 KB  row sums [B][S]

  static bool lds_opt_in = false;
  if (!lds_opt_in) {
    hipFuncSetAttribute((const void*)gemm_qv256,
                        hipFuncAttributeMaxDynamicSharedMemorySize, 163840);
    hipFuncSetAttribute((const void*)gemm_sc256,
                        hipFuncAttributeMaxDynamicSharedMemorySize, 163840);
    hipFuncSetAttribute((const void*)gemm_pv256,
                        hipFuncAttributeMaxDynamicSharedMemorySize, 163840);
    lds_opt_in = true;
  }

  prep_kernel<<<dim3(8712), 256, 0, stream>>>(x, xb, qk, qkT, ov, ovT, l);
  gemm_qv256<<<dim3(32, 1, 8), 512, 163840, stream>>>(xb, qkT, ovT, Qb, Vt);
  gemm_sc256<<<dim3(36, 1, 4), 512, 163840, stream>>>(Qb, xb, P, l);
  gemm_pv256<<<dim3(32, 1, 4), 512, 163840, stream>>>(P, Vt, l, out);
}

// Round 7
// 192.730 us; speedup vs baseline: 1.1509x; 1.1509x over previous
//
#include <hip/hip_runtime.h>
#include <hip/hip_bf16.h>
#include <cstdint>
#include <cstddef>
#include <type_traits>

// B=4, S=2048, D=1024 causal attention head, fp32 in/out.
// R12 (resubmit; R6 bench was broker infra failure — kernel never ran):
// pv rebuilt as 128x128 / 4-wave / 2-phase core, 256 perfectly-balanced
// blocks (strip-pairs r,15-r => 34 K-tiles each), 80KB LDS -> 2 blocks/CU.
// R11 evidence: per-phase time (~1170cyc) is structural; pv was bound by
// 128-block fill + 8:1 imbalance, not latency cover. qv/sc: R10 core restored.

using bf16 = __hip_bfloat16;
typedef __attribute__((ext_vector_type(8))) short short8;   // 8 bf16 (A/B frag)
typedef __attribute__((ext_vector_type(4))) float f32x4;    // C/D frag

#define NB 4
#define SS 2048
#define DD 1024

// ---------------------------------------------------------------- async 16B global->LDS
__device__ __forceinline__ void async_lds16(const bf16* g, bf16* l) {
  __builtin_amdgcn_global_load_lds(
      (const __attribute__((address_space(1))) void*)g,
      (__attribute__((address_space(3))) void*)l,
      16, 0, 0);  // HW writes lane i's 16B to ldsbase + i*16
}

struct alignas(8) bf16x4s { bf16 a, b, c, d; };

// ---------------------------------------------------------------- fused prep
__global__ __launch_bounds__(256) void prep_kernel(const float* __restrict__ x,
                                                   bf16* __restrict__ xb,
                                                   const float* __restrict__ qk,
                                                   bf16* __restrict__ qkT,
                                                   const float* __restrict__ ov,
                                                   bf16* __restrict__ ovT,
                                                   float* __restrict__ l) {
  __shared__ bf16 tile[64][65];
  const int bx = blockIdx.x;
  if (bx < 8192) {
    int i = (bx * 256 + threadIdx.x) * 4;
    float4 v = *(const float4*)(x + i);
    bf16x4s o{__float2bfloat16(v.x), __float2bfloat16(v.y),
              __float2bfloat16(v.z), __float2bfloat16(v.w)};
    *(bf16x4s*)(xb + i) = o;
  } else if (bx < 8704) {
    const int idx = bx - 8192;
    const float* in = (idx & 256) ? ov : qk;
    bf16* out = (idx & 256) ? ovT : qkT;
    const int rem = idx & 255;
    const int tbx = (rem & 15) * 64;
    const int tby = (rem >> 4) * 64;
    const int tc = threadIdx.x & 63;
    const int tr = threadIdx.x >> 6;
#pragma unroll
    for (int r = tr; r < 64; r += 4)
      tile[tc][r] = __float2bfloat16(in[(size_t)(tby + r) * DD + tbx + tc]);
    __syncthreads();
#pragma unroll
    for (int r = tr; r < 64; r += 4)
      out[(size_t)(tbx + r) * DD + tby + tc] = tile[r][tc];
  } else {
    const int t = (bx - 8704) * 256 + threadIdx.x;
    f32x4 z = {0.f, 0.f, 0.f, 0.f};
    *(f32x4*)(l + t * 4) = z;
  }
}

// ================================================================ 256^2 phased core (R8/R10-validated)
// 256x256 tile, BK=64, 8 waves (2Mx4N), acc[8][4]. 4 phases/K-tile, T2 swizzle,
// counted vmcnt (T4), setprio (T5). A/B double-buffered.
// EPI: 1 = bf16 store; 2 = exp(acc/32) causal -> bf16 + rowsum atomics.
template <int EPI>
__device__ __forceinline__ void gemm256_core(const bf16* __restrict__ Ab,
                                             const bf16* __restrict__ Bb,
                                             void* __restrict__ C,
                                             int N, int K, int m0, int n0, int nk,
                                             bf16* As, bf16* Bs,
                                             float* __restrict__ l) {
  const int lane = threadIdx.x & 63;
  const int wave = threadIdx.x >> 6;   // 0..7
  const int wr   = wave >> 2;          // 0..1 -> rows wr*128
  const int wc   = wave & 3;           // 0..3 -> cols wc*64
  const int quad = lane >> 4;
  const int r    = lane & 15;

  f32x4 acc[8][4];
#pragma unroll
  for (int i = 0; i < 8; ++i)
#pragma unroll
    for (int n = 0; n < 4; ++n) acc[i][n] = f32x4{0.f, 0.f, 0.f, 0.f};

  const int lrow = lane >> 3;
  const int lsw  = (lane & 7) ^ lrow;          // pre-swizzled source chunk
  const long long a_lane = (long long)(m0 + wave * 8 + lrow) * K + lsw * 8;
  const long long b_lane = (long long)(n0 + wave * 8 + lrow) * K + lsw * 8;

  auto stageA = [&](int kt, int rnd, int buf) {
    async_lds16(Ab + a_lane + (long long)(rnd * 64) * K + (long long)kt * 64,
                As + buf * 16384 + (rnd * 64 + wave * 8) * 64);
  };
  auto stageB = [&](int kt, int rnd, int buf) {
    async_lds16(Bb + b_lane + (long long)(rnd * 64) * K + (long long)kt * 64,
                Bs + buf * 16384 + (rnd * 64 + wave * 8) * 64);
  };

  stageA(0, 0, 0); stageA(0, 2, 0);
  stageB(0, 0, 0); stageB(0, 1, 0); stageB(0, 2, 0); stageB(0, 3, 0);
  stageA(0, 1, 0); stageA(0, 3, 0);
  asm volatile("s_waitcnt vmcnt(2)" ::: "memory");
  asm volatile("s_barrier" ::: "memory");

  const int ca0 = (quad ^ (r & 7)) * 8;        // kh=0 swizzled chunk offset
  const int ca1 = ((4 + quad) ^ (r & 7)) * 8;  // kh=1

  for (int kt = 0; kt < nk; ++kt) {
    const int buf = kt & 1, nxt = buf ^ 1;
    const bool hn = (kt + 1 < nk);
    const bf16* Abuf = As + buf * 16384 + (wr * 128) * 64;
    const bf16* Bbuf = Bs + buf * 16384 + (wc * 64) * 64;

    auto phase = [&](auto RHC, int ca, auto&& stg, int wmode) {
      constexpr int RH = decltype(RHC)::value;
      short8 af[4], bfr[4];
#pragma unroll
      for (int m = 0; m < 4; ++m)
        af[m] = *(const short8*)(Abuf + (RH * 64 + m * 16 + r) * 64 + ca);
#pragma unroll
      for (int n = 0; n < 4; ++n)
        bfr[n] = *(const short8*)(Bbuf + (n * 16 + r) * 64 + ca);
      stg();
      asm volatile("s_barrier" ::: "memory");
      asm volatile("s_waitcnt lgkmcnt(0)" ::: "memory");
      __builtin_amdgcn_sched_barrier(0);
      __builtin_amdgcn_s_setprio(1);
#pragma unroll
      for (int m = 0; m < 4; ++m)
#pragma unroll
        for (int n = 0; n < 4; ++n)
          acc[RH * 4 + m][n] = __builtin_amdgcn_mfma_f32_16x16x32_bf16(
              af[m], bfr[n], acc[RH * 4 + m][n], 0, 0, 0);
      __builtin_amdgcn_s_setprio(0);
      if (wmode == 1) {
        if (hn) asm volatile("s_waitcnt vmcnt(2)" ::: "memory");
        else    asm volatile("s_waitcnt vmcnt(0)" ::: "memory");
      } else if (wmode == 2) {
        if (hn) asm volatile("s_waitcnt vmcnt(2)" ::: "memory");
      }
      asm volatile("s_barrier" ::: "memory");
    };

    phase(std::integral_constant<int, 0>{}, ca0,
          [&] { if (hn) { stageA(kt + 1, 0, nxt); stageA(kt + 1, 2, nxt); } }, 1);
    phase(std::integral_constant<int, 1>{}, ca0,
          [&] { if (hn) { stageB(kt + 1, 0, nxt); stageB(kt + 1, 1, nxt); } }, 0);
    phase(std::integral_constant<int, 0>{}, ca1,
          [&] { if (hn) { stageB(kt + 1, 2, nxt); stageB(kt + 1, 3, nxt); } }, 0);
    phase(std::integral_constant<int, 1>{}, ca1,
          [&] { if (hn) { stageA(kt + 1, 1, nxt); stageA(kt + 1, 3, nxt); } }, 2);
  }

  // epilogue: C/D layout col = lane&15, row = quad*4 + reg (verified m89/m91)
#pragma unroll
  for (int i = 0; i < 8; ++i) {
    const int row0 = m0 + wr * 128 + i * 16 + quad * 4;
    if (EPI == 1) {
#pragma unroll
      for (int n = 0; n < 4; ++n) {
        const int col = n0 + wc * 64 + n * 16 + r;
#pragma unroll
        for (int q = 0; q < 4; ++q)
          ((bf16*)C)[(long long)(row0 + q) * N + col] = __float2bfloat16(acc[i][n][q]);
      }
    } else if (EPI == 2) {
      float qs[4] = {0.f, 0.f, 0.f, 0.f};
#pragma unroll
      for (int n = 0; n < 4; ++n) {
        const int col = n0 + wc * 64 + n * 16 + r;
#pragma unroll
        for (int q = 0; q < 4; ++q) {
          const int row = row0 + q;
          float v = (col <= row) ? __expf(acc[i][n][q] * 0.03125f) : 0.0f;
          ((bf16*)C)[(long long)row * N + col] = __float2bfloat16(v);
          qs[q] += v;
        }
      }
#pragma unroll
      for (int q = 0; q < 4; ++q) {
#pragma unroll
        for (int off = 1; off < 16; off <<= 1) qs[q] += __shfl_xor(qs[q], off, 64);
        if (r == 0) atomicAdd(&l[row0 + q], qs[q]);
      }
    }
  }
}

// ================================================================ 128^2 4-wave 2-phase core (pv)
// 128x128 tile, BK=64, 4 waves (2Mx2N), acc[4][4] per wave (64x64 out).
// LDS 80KB: A 3-buf (streaming P, 3.5-phase cover), B 2-buf (L2-warm Vt,
// 1.5-phase cover). Issue order in ph0: B(t+1) then A(t+2); end-of-tile
// vmcnt(4) retires {A(t+1),B(t),B(t+1)}, keeps A(t+2). Tail vmcnt(0) at
// t==nk-2. 2 blocks/CU -> independent barrier domains overlap drains.
__device__ __forceinline__ void gemm128_core(const bf16* __restrict__ Ab,
                                             const bf16* __restrict__ Bb,
                                             float* __restrict__ C,
                                             const float* __restrict__ l,
                                             int N, int K, int m0, int n0, int nk,
                                             bf16* As, bf16* Bs) {
  const int lane = threadIdx.x & 63;
  const int wave = threadIdx.x >> 6;   // 0..3
  const int wr   = wave >> 1;          // 0..1 -> rows wr*64
  const int wc   = wave & 1;           // 0..1 -> cols wc*64
  const int quad = lane >> 4;
  const int r    = lane & 15;

  f32x4 acc[4][4];
#pragma unroll
  for (int m = 0; m < 4; ++m)
#pragma unroll
    for (int n = 0; n < 4; ++n) acc[m][n] = f32x4{0.f, 0.f, 0.f, 0.f};

  const int lrow = lane >> 3;
  const int lsw  = (lane & 7) ^ lrow;  // pre-swizzled source chunk (T2)
  const long long a_base = (long long)(m0 + wave * 32 + lrow) * K + lsw * 8;
  const long long b_base = (long long)(n0 + wave * 32 + lrow) * K + lsw * 8;

  auto stageA = [&](int kt, int buf) {
#pragma unroll
    for (int i = 0; i < 4; ++i)
      async_lds16(Ab + a_base + (long long)(i * 8) * K + (long long)kt * 64,
                  As + buf * 8192 + (wave * 32 + i * 8) * 64);
  };
  auto stageB = [&](int kt, int buf) {
#pragma unroll
    for (int i = 0; i < 4; ++i)
      async_lds16(Bb + b_base + (long long)(i * 8) * K + (long long)kt * 64,
                  Bs + buf * 8192 + (wave * 32 + i * 8) * 64);
  };

  // prologue: B(0),A(0)->buf0; A(1)->bufA1. vmcnt(4) keeps A(1) in flight.
  stageB(0, 0); stageA(0, 0); stageA(1, 1);
  asm volatile("s_waitcnt vmcnt(4)" ::: "memory");
  asm volatile("s_barrier" ::: "memory");

  const int ca0 = (quad ^ (r & 7)) * 8;
  const int ca1 = ((4 + quad) ^ (r & 7)) * 8;

  int ba = 0;                           // A buffer = kt % 3
  for (int kt = 0; kt < nk; ++kt) {
    const int bb = kt & 1;
    int ba2 = ba + 2; if (ba2 >= 3) ba2 -= 3;
    const bool hA = (kt + 2 < nk), hB = (kt + 1 < nk);
    const bf16* Abuf = As + ba * 8192;
    const bf16* Bbuf = Bs + bb * 8192;

    auto phase = [&](int ca, auto&& stg, bool tail) {
      short8 af[4], bfr[4];
#pragma unroll
      for (int m = 0; m < 4; ++m)
        af[m] = *(const short8*)(Abuf + (wr * 64 + m * 16 + r) * 64 + ca);
#pragma unroll
      for (int n = 0; n < 4; ++n)
        bfr[n] = *(const short8*)(Bbuf + (wc * 64 + n * 16 + r) * 64 + ca);
      stg();
      asm volatile("s_barrier" ::: "memory");
      asm volatile("s_waitcnt lgkmcnt(0)" ::: "memory");
      __builtin_amdgcn_sched_barrier(0);
      __builtin_amdgcn_s_setprio(1);
#pragma unroll
      for (int m = 0; m < 4; ++m)
#pragma unroll
        for (int n = 0; n < 4; ++n)
          acc[m][n] = __builtin_amdgcn_mfma_f32_16x16x32_bf16(
              af[m], bfr[n], acc[m][n], 0, 0, 0);
      __builtin_amdgcn_s_setprio(0);
      if (tail) {
        if (hA)      asm volatile("s_waitcnt vmcnt(4)" ::: "memory");
        else if (hB) asm volatile("s_waitcnt vmcnt(0)" ::: "memory");
      }
      asm volatile("s_barrier" ::: "memory");
    };

    phase(ca0, [&] { if (hB) stageB(kt + 1, bb ^ 1);
                     if (hA) stageA(kt + 2, ba2); }, false);
    phase(ca1, [&] {}, true);

    if (++ba == 3) ba = 0;
  }

  // epilogue: acc * (1/l[row]) -> f32  (C/D layout verified m89/m91)
#pragma unroll
  for (int m = 0; m < 4; ++m) {
    const int row0 = m0 + wr * 64 + m * 16 + quad * 4;
    float rs[4];
#pragma unroll
    for (int q = 0; q < 4; ++q) rs[q] = 1.0f / l[row0 + q];
#pragma unroll
    for (int n = 0; n < 4; ++n) {
      const int col = n0 + wc * 64 + n * 16 + r;
#pragma unroll
      for (int q = 0; q < 4; ++q)
        C[(long long)(row0 + q) * N + col] = acc[m][n][q] * rs[q];
    }
  }
}

// ---------------------------------------------------------------- merged Q + V GEMM (256^2)
__global__ __launch_bounds__(512, 2) void gemm_qv256(const bf16* __restrict__ xb,
                                                     const bf16* __restrict__ qkT,
                                                     const bf16* __restrict__ ovT,
                                                     bf16* __restrict__ Qb,
                                                     bf16* __restrict__ Vt) {
  extern __shared__ bf16 lds[];
  bf16* As = lds;            // [2][256][64]
  bf16* Bs = lds + 32768;    // [2][256][64]
  const long long SD = (long long)SS * DD;
  const int z = blockIdx.z;
  if (z < 4) {
    const int bn = blockIdx.x & 3, bm = blockIdx.x >> 2;
    gemm256_core<1>(xb + z * SD, qkT, Qb + z * SD, DD, DD, bm * 256, bn * 256, 16,
                    As, Bs, nullptr);
  } else {
    const int bm = blockIdx.x & 3, bn = blockIdx.x >> 2;
    gemm256_core<1>(ovT, xb + (z - 4) * SD, Vt + (z - 4) * SD, SS, DD, bm * 256, bn * 256, 16,
                    As, Bs, nullptr);
  }
}

// ---------------------------------------------------------------- scores GEMM (256^2) + exp/mask/rowsum
__global__ __launch_bounds__(512, 2) void gemm_sc256(const bf16* __restrict__ Qb,
                                                     const bf16* __restrict__ xb,
                                                     bf16* __restrict__ P,
                                                     float* __restrict__ l) {
  extern __shared__ bf16 lds[];
  bf16* As = lds;
  bf16* Bs = lds + 32768;
  const long long SD = (long long)SS * DD;
  const long long SSQ = (long long)SS * SS;
  const int t = blockIdx.x;
  int bm = (int)((sqrtf(8.0f * (float)t + 1.0f) - 1.0f) * 0.5f);
  while ((bm + 1) * (bm + 2) / 2 <= t) ++bm;
  while (bm * (bm + 1) / 2 > t) --bm;
  const int bn = t - bm * (bm + 1) / 2;
  const int b = blockIdx.z;
  gemm256_core<2>(Qb + b * SD, xb + b * SD, P + b * SSQ, SS, DD, bm * 256, bn * 256, 16,
                  As, Bs, l + b * SS);
}

// ---------------------------------------------------------------- PV GEMM (128^2, balanced pairs)
// Grid (64,1,4): c = x&7 (128-wide D col-tile), pr = x>>3 (strip pair).
// Block does strip 15-pr (nk=2(16-pr)) then strip pr (nk=2(pr+1)):
// exactly 34 K-tiles per block, 256 blocks, 2 blocks/CU (80KB LDS).
// XCD ~ c: one 512KB Vt row-panel x4 batches pinned per L2.
__global__ __launch_bounds__(256, 2) void gemm_pv128(const bf16* __restrict__ P,
                                                     const bf16* __restrict__ Vt,
                                                     const float* __restrict__ l,
                                                     float* __restrict__ out) {
  extern __shared__ bf16 lds[];
  bf16* As = lds;            // [3][128][64] = 48KB
  bf16* Bs = lds + 24576;    // [2][128][64] = 32KB
  const long long SD = (long long)SS * DD;
  const long long SSQ = (long long)SS * SS;
  const int c  = blockIdx.x & 7;
  const int pr = blockIdx.x >> 3;
  const int b  = blockIdx.z;
  const int n0 = c * 128;
  const int rL = 15 - pr;
  gemm128_core(P + b * SSQ, Vt + b * SD, out + b * SD, (const float*)l + b * SS,
               DD, SS, rL * 128, n0, 2 * (rL + 1), As, Bs);
  __syncthreads();
  gemm128_core(P + b * SSQ, Vt + b * SD, out + b * SD, (const float*)l + b * SS,
               DD, SS, pr * 128, n0, 2 * (pr + 1), As, Bs);
}

// ---------------------------------------------------------------- launch
extern "C" void kernel_launch(void* const* d_in, const int* in_sizes, int n_in,
                              void* d_out, int out_size, void* d_ws, size_t ws_size,
                              hipStream_t stream) {
  const float* x  = (const float*)d_in[0];  // [4,2048,1024]
  const float* qk = (const float*)d_in[1];  // [1024,1024]
  const float* ov = (const float*)d_in[2];  // [1024,1024]
  float* out = (float*)d_out;               // [4,2048,1024] fp32

  char* ws = (char*)d_ws;
  const size_t MB = 1ull << 20;
  bf16*  xb  = (bf16*)(ws + 0);          // 16 MB
  bf16*  qkT = (bf16*)(ws + 16 * MB);    //  2 MB
  bf16*  ovT = (bf16*)(ws + 18 * MB);    //  2 MB
  bf16*  Qb  = (bf16*)(ws + 20 * MB);    // 16 MB
  bf16*  Vt  = (bf16*)(ws + 36 * MB);    // 16 MB  V^T per batch [D, S]
  bf16*  P   = (bf16*)(ws + 52 * MB);    // 32 MB  P' = exp(s/32) bf16
  float* l   = (float*)(ws + 84 * MB);   // 32 KB  row sums [B][S]

  static bool lds_opt_in = false;
  if (!lds_opt_in) {
    hipFuncSetAttribute((const void*)gemm_qv256,
                        hipFuncAttributeMaxDynamicSharedMemorySize, 131072);
    hipFuncSetAttribute((const void*)gemm_sc256,
                        hipFuncAttributeMaxDynamicSharedMemorySize, 131072);
    hipFuncSetAttribute((const void*)gemm_pv128,
                        hipFuncAttributeMaxDynamicSharedMemorySize, 81920);
    lds_opt_in = true;
  }

  prep_kernel<<<dim3(8712), 256, 0, stream>>>(x, xb, qk, qkT, ov, ovT, l);
  gemm_qv256<<<dim3(32, 1, 8), 512, 131072, stream>>>(xb, qkT, ovT, Qb, Vt);
  gemm_sc256<<<dim3(36, 1, 4), 512, 131072, stream>>>(Qb, xb, P, l);
  gemm_pv128<<<dim3(64, 1, 4), 256, 81920, stream>>>(P, Vt, l, out);
}